// Round 1
// baseline (577045.459 us; speedup 1.0000x reference)
//
#include <hip/hip_runtime.h>
#include <math.h>

// MGU RNN: T=8192 steps, IN=128, H=1024, L=3 layers.
// Strategy: persistent per-layer scan kernel. 256 WGs x 256 threads (1 WG/CU).
// Wave u of WG g owns hidden unit j = g*4+u. W_hh rows for owned units live in
// LDS for the whole scan; W_ih rows are read from global (L1/L2-hot).
// Cross-WG per-step sync: monotone per-WG flags + spin, h double-buffered,
// agent-scope atomics + fences for cross-XCD visibility.

#define T_STEPS 8192
#define HDIM 1024

__device__ __forceinline__ float wave_reduce(float v) {
#pragma unroll
    for (int off = 32; off > 0; off >>= 1) v += __shfl_xor(v, off, 64);
    return v;
}

template <int K>
__global__ __launch_bounds__(256)
void mgu_scan(const float* __restrict__ x_in,   // [T, K]  layer input
              const float* __restrict__ w_ih,   // [2H, K]
              const float* __restrict__ b_ih,   // [2H]
              const float* __restrict__ w_hh,   // [2H, H]
              const float* __restrict__ b_hh,   // [2H]
              float* __restrict__ x_out,        // [T, H]  layer output
              float* __restrict__ h_buf,        // [2, H]  double-buffered state
              int* __restrict__ flags)          // [256]   per-WG progress
{
    __shared__ __align__(16) float s_whf[4][HDIM];  // W_hh rows j      (forget)
    __shared__ __align__(16) float s_whn[4][HDIM];  // W_hh rows H+j    (new)
    __shared__ __align__(16) float s_h[HDIM];
    __shared__ __align__(16) float s_x[K];

    const int tid  = threadIdx.x;
    const int g    = blockIdx.x;      // 0..255
    const int wave = tid >> 6;        // 0..3
    const int lane = tid & 63;
    const int j    = g * 4 + wave;    // owned hidden unit

    // ---- stage W_hh slice into LDS (once) ----
#pragma unroll
    for (int u = 0; u < 4; ++u) {
        const int jj = g * 4 + u;
        const float4* srcf = (const float4*)(w_hh + (size_t)jj * HDIM);
        const float4* srcn = (const float4*)(w_hh + (size_t)(HDIM + jj) * HDIM);
        ((float4*)s_whf[u])[tid] = srcf[tid];   // 256 thr x float4 = 1024 f32
        ((float4*)s_whn[u])[tid] = srcn[tid];
    }

    const float bIf = b_ih[j];
    const float bIn = b_ih[HDIM + j];
    const float bHf = b_hh[j];
    const float bHn = b_hh[HDIM + j];
    const float* __restrict__ wif_row = w_ih + (size_t)j * K;
    const float* __restrict__ win_row = w_ih + (size_t)(HDIM + j) * K;

    __syncthreads();

    for (int t = 0; t < T_STEPS; ++t) {
        // ---- 1. wait until every WG has published step t-1 ----
        if (t > 0) {
            for (;;) {
                int v = __hip_atomic_load(&flags[tid], __ATOMIC_RELAXED,
                                          __HIP_MEMORY_SCOPE_AGENT);
                if (__syncthreads_count(v >= t) == 256) break;
            }
            __threadfence();   // acquire: invalidate stale cached h lines
        }
        const float* hcur = h_buf + ((t & 1) ? HDIM : 0);
        float*       hnxt = h_buf + ((t & 1) ? 0 : HDIM);

        // ---- 2. stage h_{t-1} and x_t into LDS ----
        ((float4*)s_h)[tid] = ((const float4*)hcur)[tid];
        if constexpr (K == 128) {
            if (tid < 32)
                ((float4*)s_x)[tid] = ((const float4*)(x_in + (size_t)t * K))[tid];
        } else {
            ((float4*)s_x)[tid] = ((const float4*)(x_in + (size_t)t * K))[tid];
        }
        __syncthreads();

        // ---- 3. dot products for unit j ----
        float accF = 0.f, accNh = 0.f, accNi = 0.f;
#pragma unroll
        for (int m = 0; m < 4; ++m) {
            const int i4 = lane + 64 * m;
            const float4 h4 = ((const float4*)s_h)[i4];
            const float4 wf = ((const float4*)s_whf[wave])[i4];
            const float4 wn = ((const float4*)s_whn[wave])[i4];
            accF  += wf.x * h4.x + wf.y * h4.y + wf.z * h4.z + wf.w * h4.w;
            accNh += wn.x * h4.x + wn.y * h4.y + wn.z * h4.z + wn.w * h4.w;
        }
        if constexpr (K == 128) {
            const float2 x2 = ((const float2*)s_x)[lane];
            const float2 wf = ((const float2*)wif_row)[lane];
            const float2 wn = ((const float2*)win_row)[lane];
            accF  += wf.x * x2.x + wf.y * x2.y;
            accNi += wn.x * x2.x + wn.y * x2.y;
        } else {
#pragma unroll
            for (int m = 0; m < K / 256; ++m) {
                const int i4 = lane + 64 * m;
                const float4 x4 = ((const float4*)s_x)[i4];
                const float4 wf = ((const float4*)wif_row)[i4];
                const float4 wn = ((const float4*)win_row)[i4];
                accF  += wf.x * x4.x + wf.y * x4.y + wf.z * x4.z + wf.w * x4.w;
                accNi += wn.x * x4.x + wn.y * x4.y + wn.z * x4.z + wn.w * x4.w;
            }
        }
        accF  = wave_reduce(accF);
        accNh = wave_reduce(accNh);
        accNi = wave_reduce(accNi);

        // ---- 4. gates + state update (lane 0 of each wave) ----
        if (lane == 0) {
            const float f  = 1.f / (1.f + expf(-(accF + bIf + bHf)));
            const float n  = tanhf(accNi + bIn + f * (accNh + bHn));
            const float hy = n + (1.f - f) * (s_h[j] - n);
            // device-scope store: must reach MALL for cross-XCD readers
            __hip_atomic_store(&hnxt[j], hy, __ATOMIC_RELAXED,
                               __HIP_MEMORY_SCOPE_AGENT);
            x_out[(size_t)t * HDIM + j] = hy;
        }
        __syncthreads();   // drains vmcnt: all 4 waves' stores complete
        if (tid == 0) {
            __threadfence();   // release: push anything L2-resident to MALL
            __hip_atomic_store(&flags[g], t + 1, __ATOMIC_RELAXED,
                               __HIP_MEMORY_SCOPE_AGENT);
        }
    }
}

__global__ void mgu_init(const float* __restrict__ h0,   // [3, H]
                         float* __restrict__ h_all,      // [3][2][H]
                         int* __restrict__ flags_all)    // [3][256]
{
    const int l = blockIdx.x;   // layer
    const int i = threadIdx.x;  // 0..1023
    h_all[l * 2 * HDIM + i] = h0[l * HDIM + i];   // buffer 0 = h0
    if (i < 256) flags_all[l * 256 + i] = 0;
}

__global__ __launch_bounds__(256)
void mgu_out(const float* __restrict__ x,       // [T, H]
             const float* __restrict__ w_out,   // [1, H]
             const float* __restrict__ b_out,   // [1]
             float* __restrict__ out)           // [T]
{
    const int wave = threadIdx.x >> 6;
    const int lane = threadIdx.x & 63;
    const int t = blockIdx.x * 4 + wave;
    float acc = 0.f;
#pragma unroll
    for (int m = 0; m < 4; ++m) {
        const int i4 = lane + 64 * m;
        const float4 x4 = ((const float4*)(x + (size_t)t * HDIM))[i4];
        const float4 w4 = ((const float4*)w_out)[i4];
        acc += x4.x * w4.x + x4.y * w4.y + x4.z * w4.z + x4.w * w4.w;
    }
    acc = wave_reduce(acc);
    if (lane == 0) out[t] = acc + b_out[0];
}

extern "C" void kernel_launch(void* const* d_in, const int* in_sizes, int n_in,
                              void* d_out, int out_size, void* d_ws, size_t ws_size,
                              hipStream_t stream) {
    const float* S      = (const float*)d_in[0];   // [8192,128]
    const float* h0     = (const float*)d_in[1];   // [3,1024]
    const float* w_ih0  = (const float*)d_in[2];   // [2048,128]
    const float* w_hh0  = (const float*)d_in[3];   // [2048,1024]
    const float* b_ih0  = (const float*)d_in[4];   // [2048]
    const float* b_hh0  = (const float*)d_in[5];   // [2048]
    const float* w_ih_r = (const float*)d_in[6];   // [2,2048,1024]
    const float* w_hh_r = (const float*)d_in[7];   // [2,2048,1024]
    const float* b_ih_r = (const float*)d_in[8];   // [2,2048]
    const float* b_hh_r = (const float*)d_in[9];   // [2,2048]
    const float* w_out  = (const float*)d_in[10];  // [1,1024]
    const float* b_out  = (const float*)d_in[11];  // [1]
    float* out = (float*)d_out;                    // [8192]

    char* ws = (char*)d_ws;
    float* xA        = (float*)(ws);                          // 32 MB [T,H]
    float* xB        = (float*)(ws + (32u << 20));            // 32 MB [T,H]
    float* h_all     = (float*)(ws + (64u << 20));            // 3*2*1024 f32
    int*   flags_all = (int*)  (ws + (64u << 20) + 32768);    // 3*256 int

    mgu_init<<<3, 1024, 0, stream>>>(h0, h_all, flags_all);

    // layer 0: S -> xA
    mgu_scan<128><<<256, 256, 0, stream>>>(
        S, w_ih0, b_ih0, w_hh0, b_hh0, xA, h_all + 0, flags_all + 0);
    // layer 1: xA -> xB
    mgu_scan<1024><<<256, 256, 0, stream>>>(
        xA, w_ih_r, b_ih_r, w_hh_r, b_hh_r, xB,
        h_all + 2 * HDIM, flags_all + 256);
    // layer 2: xB -> xA
    mgu_scan<1024><<<256, 256, 0, stream>>>(
        xB, w_ih_r + 2048 * 1024, b_ih_r + 2048,
        w_hh_r + 2048 * 1024, b_hh_r + 2048, xA,
        h_all + 4 * HDIM, flags_all + 512);
    // output projection
    mgu_out<<<2048, 256, 0, stream>>>(xA, w_out, b_out, out);
}

// Round 2
// 47593.533 us; speedup vs baseline: 12.1245x; 12.1245x over previous
//
#include <hip/hip_runtime.h>
#include <math.h>

// MGU RNN, T=8192, IN=128, H=1024, L=3 — pipelined persistent kernel.
// 192 WGs = 3 layer-groups x 64 WGs. WG r of group l owns hidden units
// [r*16, r*16+16). All weights (W_hh + W_ih rows) live in REGISTERS
// (~256 VGPR/thread; 256 thr = 4 waves = 1 wave/SIMD, so up to 512 VGPR free).
// Cross-WG sync: relaxed agent-scope atomics only (sc0sc1 -> MALL), NO
// threadfence (no buffer_wbl2/buffer_inv). Publisher order: data stores ->
// __syncthreads (compiler drains vmcnt(0) per wave) -> flag store.
// Layers pipelined: layer l works on step t once layer l-1 published step t
// (flags[l-1][*] >= t+1) and its own step t-1 is done (flags[l][*] >= t).
// Inter-layer x through 16-row ring buffers with flag backpressure.

#define T_STEPS 8192
#define HDIM 1024
#define RING 16
#define WGS 64        // WGs per layer group
#define UNITS 16      // hidden units per WG

__device__ __forceinline__ float agloadf(const float* p) {
    return __hip_atomic_load((const float*)p, __ATOMIC_RELAXED,
                             __HIP_MEMORY_SCOPE_AGENT);
}
__device__ __forceinline__ void agstoref(float* p, float v) {
    __hip_atomic_store(p, v, __ATOMIC_RELAXED, __HIP_MEMORY_SCOPE_AGENT);
}
__device__ __forceinline__ int agloadi(const int* p) {
    return __hip_atomic_load((const int*)p, __ATOMIC_RELAXED,
                             __HIP_MEMORY_SCOPE_AGENT);
}
__device__ __forceinline__ void agstorei(int* p, int v) {
    __hip_atomic_store(p, v, __ATOMIC_RELAXED, __HIP_MEMORY_SCOPE_AGENT);
}
__device__ __forceinline__ float dot4(float4 a, float4 b) {
    return a.x * b.x + a.y * b.y + a.z * b.z + a.w * b.w;
}

// K: input width (128 layer 0, 1024 otherwise). L: layer index 0..2.
template <int K, int L>
__device__ void scan_layer(const float* __restrict__ xsrc, // L==0: S[T,K]; else ring_{L-1}[RING,H]
                           const float* __restrict__ h0,   // [H] this layer's h0
                           const float* __restrict__ w_ih, // [2H, K]
                           const float* __restrict__ b_ih, // [2H]
                           const float* __restrict__ w_hh, // [2H, H]
                           const float* __restrict__ b_hh, // [2H]
                           float* __restrict__ dst,        // L==2: xbuf2[T,H]; else ring_L
                           int* __restrict__ flagsL,       // [WGS] own group
                           const int* __restrict__ flagsP, // [WGS] prev group (L>0)
                           const int* __restrict__ flagsN, // [WGS] next group (L<2)
                           int r)                          // WG index within group
{
    __shared__ __align__(16) float s_h[HDIM];
    __shared__ __align__(16) float s_x[K];

    const int tid = threadIdx.x;
    const int u   = tid >> 4;          // unit 0..15 within WG
    const int q   = tid & 15;          // k-slice 0..15 within unit
    const int j   = r * UNITS + u;     // global hidden unit

    // ---- weights -> registers (once). Fixed indices after unroll. ----
    float4 whf[16], whn[16];           // W_hh rows j (forget) and H+j (new)
    float4 wif[K / 64], win[K / 64];   // W_ih rows j and H+j
#pragma unroll
    for (int m = 0; m < 16; ++m) {
        whf[m] = *(const float4*)(w_hh + (size_t)j * HDIM + 4 * (q + 16 * m));
        whn[m] = *(const float4*)(w_hh + (size_t)(HDIM + j) * HDIM + 4 * (q + 16 * m));
    }
#pragma unroll
    for (int m = 0; m < K / 64; ++m) {
        wif[m] = *(const float4*)(w_ih + (size_t)j * K + 4 * (q + 16 * m));
        win[m] = *(const float4*)(w_ih + (size_t)(HDIM + j) * K + 4 * (q + 16 * m));
    }
    const float bF  = b_ih[j] + b_hh[j];
    const float bIn = b_ih[HDIM + j];
    const float bHn = b_hh[HDIM + j];

    for (int t = 0; t < T_STEPS; ++t) {
        // ---- spin: wave 0 polls, barrier releases the WG ----
        if (tid < 64) {
            const int w = tid;
            for (;;) {
                bool ok = (w < WGS) ? (agloadi(&flagsL[w]) >= t) : true;
                if constexpr (L > 0) {
                    if (w < WGS) ok = ok && (agloadi(&flagsP[w]) >= t + 1);
                }
                if constexpr (L < 2) {
                    // ring slot (t % RING) free once next group consumed row t-RING
                    if (w < WGS) ok = ok && (agloadi(&flagsN[w]) >= t - (RING - 1));
                }
                if (__all(ok)) break;
            }
        }
        __syncthreads();

        // ---- gather h_{t-1} into LDS ----
        if (t == 0) {
            ((float4*)s_h)[tid] = ((const float4*)h0)[tid];
        } else {
            const float* hrow = (L == 2)
                ? dst + (size_t)(t - 1) * HDIM
                : dst + (size_t)((t - 1) & (RING - 1)) * HDIM;
#pragma unroll
            for (int i = 0; i < 4; ++i)
                s_h[tid + 256 * i] = agloadf(hrow + tid + 256 * i);
        }
        // ---- gather x_t into LDS ----
        if constexpr (L == 0) {
            if (tid < K / 4)
                ((float4*)s_x)[tid] = ((const float4*)(xsrc + (size_t)t * K))[tid];
        } else {
            const float* xrow = xsrc + (size_t)(t & (RING - 1)) * HDIM;
#pragma unroll
            for (int i = 0; i < 4; ++i)
                s_x[tid + 256 * i] = agloadf(xrow + tid + 256 * i);
        }
        __syncthreads();

        // ---- dots: unit j, k-slice q (strided float4) ----
        float aF = 0.f, aNi = 0.f, aNh = 0.f;
#pragma unroll
        for (int m = 0; m < 16; ++m) {
            const float4 h4 = ((const float4*)s_h)[q + 16 * m];
            aF  += dot4(whf[m], h4);
            aNh += dot4(whn[m], h4);
        }
#pragma unroll
        for (int m = 0; m < K / 64; ++m) {
            const float4 x4 = ((const float4*)s_x)[q + 16 * m];
            aF  += dot4(wif[m], x4);
            aNi += dot4(win[m], x4);
        }
#pragma unroll
        for (int off = 8; off > 0; off >>= 1) {
            aF  += __shfl_xor(aF, off, 64);
            aNi += __shfl_xor(aNi, off, 64);
            aNh += __shfl_xor(aNh, off, 64);
        }

        // ---- gate + publish (one lane per unit) ----
        if (q == 0) {
            const float f  = 1.f / (1.f + expf(-(aF + bF)));
            const float n  = tanhf(aNi + bIn + f * (aNh + bHn));
            const float hp = s_h[j];
            const float hy = n + (1.f - f) * (hp - n);
            float* orow = (L == 2)
                ? dst + (size_t)t * HDIM
                : dst + (size_t)(t & (RING - 1)) * HDIM;
            agstoref(orow + j, hy);
        }
        __syncthreads();   // per-wave vmcnt(0) before s_barrier drains stores
        if (tid == 0) agstorei(&flagsL[r], t + 1);
    }
}

__global__ __launch_bounds__(256, 1)
void mgu_pipe(const float* __restrict__ S,
              const float* __restrict__ h0,
              const float* __restrict__ w_ih0, const float* __restrict__ b_ih0,
              const float* __restrict__ w_hh0, const float* __restrict__ b_hh0,
              const float* __restrict__ w_ih_r, const float* __restrict__ b_ih_r,
              const float* __restrict__ w_hh_r, const float* __restrict__ b_hh_r,
              float* __restrict__ xbuf2, float* __restrict__ ring0,
              float* __restrict__ ring1, int* __restrict__ flags)
{
    const int grp = blockIdx.x >> 6;
    const int r   = blockIdx.x & 63;
    if (grp == 0) {
        scan_layer<128, 0>(S, h0, w_ih0, b_ih0, w_hh0, b_hh0,
                           ring0, flags, nullptr, flags + 64, r);
    } else if (grp == 1) {
        scan_layer<1024, 1>(ring0, h0 + HDIM, w_ih_r, b_ih_r, w_hh_r, b_hh_r,
                            ring1, flags + 64, flags, flags + 128, r);
    } else {
        scan_layer<1024, 2>(ring1, h0 + 2 * HDIM,
                            w_ih_r + 2048 * 1024, b_ih_r + 2048,
                            w_hh_r + 2048 * 1024, b_hh_r + 2048,
                            xbuf2, flags + 128, flags + 64, nullptr, r);
    }
}

__global__ void mgu_init(int* __restrict__ flags) {
    if (threadIdx.x < 192) flags[threadIdx.x] = 0;
}

__global__ __launch_bounds__(256)
void mgu_out(const float* __restrict__ x,       // [T, H]
             const float* __restrict__ w_out,   // [1, H]
             const float* __restrict__ b_out,   // [1]
             float* __restrict__ out)           // [T]
{
    const int wave = threadIdx.x >> 6;
    const int lane = threadIdx.x & 63;
    const int t = blockIdx.x * 4 + wave;
    float acc = 0.f;
#pragma unroll
    for (int m = 0; m < 4; ++m) {
        const int i4 = lane + 64 * m;
        const float4 x4 = ((const float4*)(x + (size_t)t * HDIM))[i4];
        const float4 w4 = ((const float4*)w_out)[i4];
        acc += dot4(x4, w4);
    }
#pragma unroll
    for (int off = 32; off > 0; off >>= 1) acc += __shfl_xor(acc, off, 64);
    if (lane == 0) out[t] = acc + b_out[0];
}

extern "C" void kernel_launch(void* const* d_in, const int* in_sizes, int n_in,
                              void* d_out, int out_size, void* d_ws, size_t ws_size,
                              hipStream_t stream) {
    const float* S      = (const float*)d_in[0];   // [8192,128]
    const float* h0     = (const float*)d_in[1];   // [3,1024]
    const float* w_ih0  = (const float*)d_in[2];   // [2048,128]
    const float* w_hh0  = (const float*)d_in[3];   // [2048,1024]
    const float* b_ih0  = (const float*)d_in[4];   // [2048]
    const float* b_hh0  = (const float*)d_in[5];   // [2048]
    const float* w_ih_r = (const float*)d_in[6];   // [2,2048,1024]
    const float* w_hh_r = (const float*)d_in[7];   // [2,2048,1024]
    const float* b_ih_r = (const float*)d_in[8];   // [2,2048]
    const float* b_hh_r = (const float*)d_in[9];   // [2,2048]
    const float* w_out  = (const float*)d_in[10];  // [1,1024]
    const float* b_out  = (const float*)d_in[11];  // [1]
    float* out = (float*)d_out;                    // [8192]

    char* ws = (char*)d_ws;
    float* xbuf2 = (float*)(ws);                               // 32 MB [T,H]
    float* ring0 = (float*)(ws + (32u << 20));                 // 64 KB
    float* ring1 = (float*)(ws + (32u << 20) + (64u << 10));   // 64 KB
    int*   flags = (int*)  (ws + (32u << 20) + (128u << 10));  // 192 ints

    mgu_init<<<1, 256, 0, stream>>>(flags);
    mgu_pipe<<<192, 256, 0, stream>>>(S, h0, w_ih0, b_ih0, w_hh0, b_hh0,
                                      w_ih_r, b_ih_r, w_hh_r, b_hh_r,
                                      xbuf2, ring0, ring1, flags);
    mgu_out<<<2048, 256, 0, stream>>>(xbuf2, w_out, b_out, out);
}

// Round 3
// 44887.482 us; speedup vs baseline: 12.8554x; 1.0603x over previous
//
#include <hip/hip_runtime.h>
#include <math.h>
#include <stdint.h>

// MGU RNN, T=8192, IN=128, H=1024, L=3 — pipelined persistent kernel, R3.
// 192 WGs = 3 layer-groups x 64 WGs; WG r of a group owns units [16r,16r+16).
// Sync: TAGGED DATA. Each h/x element is a 64-bit (tag<<32 | float-bits) word
// stored with one relaxed agent-scope atomic (sc0 sc1 -> MALL, no fences).
// Consumers poll the data words for tag==expected (exact match; 0xAA poison
// never matches -> no init needed). One MALL hop per step instead of three.
// W_hh lives in LDS (128KB/WG, staged once); W_ih in registers. s_h/s_x are
// double-buffered by step parity -> exactly ONE __syncthreads per step.
// x handoff: 128-row tagged rings; backpressure via per-layer progress word
// polled only when the producer is >RING-8 steps ahead (amortized).

#define T_STEPS 8192
#define HDIM 1024
#define RING 128
#define WGS 64
#define UNITS 16

typedef unsigned long long u64;

__device__ __forceinline__ u64 agload64(const u64* p) {
    return __hip_atomic_load(p, __ATOMIC_RELAXED, __HIP_MEMORY_SCOPE_AGENT);
}
__device__ __forceinline__ void agstore64(u64* p, u64 v) {
    __hip_atomic_store(p, v, __ATOMIC_RELAXED, __HIP_MEMORY_SCOPE_AGENT);
}
__device__ __forceinline__ int agloadi(const int* p) {
    return __hip_atomic_load(p, __ATOMIC_RELAXED, __HIP_MEMORY_SCOPE_AGENT);
}
__device__ __forceinline__ void agstorei(int* p, int v) {
    __hip_atomic_store(p, v, __ATOMIC_RELAXED, __HIP_MEMORY_SCOPE_AGENT);
}
__device__ __forceinline__ float dot4(float4 a, float4 b) {
    return a.x * b.x + a.y * b.y + a.z * b.z + a.w * b.w;
}
__device__ __forceinline__ u64 pack(float v, int tag) {
    return ((u64)(unsigned)tag << 32) | (u64)__float_as_uint(v);
}

struct SmemT {
    float whh[2][UNITS][HDIM + 4];   // [forget|new][unit][k] +4 pad: 131584 B
    float h[2][HDIM];                // step-parity double buffer: 8192 B
    float x[2][HDIM];                // step-parity double buffer: 8192 B
};                                   // total 147968 B < 160 KiB

// K: input width. L: layer index 0..2.
template <int K, int L>
__device__ void scan_layer(SmemT& sm,
                           const float* __restrict__ S,         // L==0: [T,K]
                           const u64*  __restrict__ xring_in,   // L>0: [RING,H]
                           u64*        __restrict__ xring_out,  // L<2: [RING,H]
                           float*      __restrict__ xout,       // L==2: [T,H]
                           const float* __restrict__ h0,        // [H]
                           const float* __restrict__ w_ih,
                           const float* __restrict__ b_ih,
                           const float* __restrict__ w_hh,
                           const float* __restrict__ b_hh,
                           u64* __restrict__ htag,              // [2,H] tagged
                           int* __restrict__ progNext,          // L<2
                           int* __restrict__ progSelf,          // L>0
                           int r)
{
    const int tid = threadIdx.x;
    const int u   = tid >> 4;        // unit 0..15 within WG
    const int q   = tid & 15;        // k-slice 0..15 within unit
    const int j   = r * UNITS + u;   // global hidden unit

    // ---- stage W_hh slice into LDS (once) ----
#pragma unroll 4
    for (int half = 0; half < 2; ++half)
        for (int uu = 0; uu < UNITS; ++uu) {
            const float* src = w_hh + (size_t)(half * HDIM + r * UNITS + uu) * HDIM;
            ((float4*)&sm.whh[half][uu][0])[tid] = ((const float4*)src)[tid];
        }

    // ---- W_ih rows -> registers (modest count: K/64 float4 per array) ----
    float4 wif[K / 64], win[K / 64];
#pragma unroll
    for (int m = 0; m < K / 64; ++m) {
        wif[m] = *(const float4*)(w_ih + (size_t)j * K + 4 * (q + 16 * m));
        win[m] = *(const float4*)(w_ih + (size_t)(HDIM + j) * K + 4 * (q + 16 * m));
    }
    const float bF  = b_ih[j] + b_hh[j];
    const float bIn = b_ih[HDIM + j];
    const float bHn = b_hh[HDIM + j];

    __syncthreads();   // W_hh staged

    int lastProg = 0;
    for (int t = 0; t < T_STEPS; ++t) {
        const int par = t & 1;

        // ---- amortized ring backpressure (off critical path in steady state)
        if constexpr (L < 2) {
            if (t - lastProg > RING - 8) {
                do { lastProg = agloadi(progNext); } while (t - lastProg > RING - 8);
            }
        }

        // ---- gather h_{t-1}: poll tagged data, land in LDS ----
        if (t == 0) {
            ((float4*)sm.h[0])[tid] = ((const float4*)h0)[tid];
        } else {
            const u64* hrow = htag + (size_t)((t - 1) & 1) * HDIM;
            const unsigned exp = (unsigned)t;
            u64 v0, v1, v2, v3;
            for (;;) {
                v0 = agload64(hrow + tid);
                v1 = agload64(hrow + tid + 256);
                v2 = agload64(hrow + tid + 512);
                v3 = agload64(hrow + tid + 768);
                if ((unsigned)(v0 >> 32) == exp && (unsigned)(v1 >> 32) == exp &&
                    (unsigned)(v2 >> 32) == exp && (unsigned)(v3 >> 32) == exp)
                    break;
            }
            sm.h[par][tid]       = __uint_as_float((unsigned)v0);
            sm.h[par][tid + 256] = __uint_as_float((unsigned)v1);
            sm.h[par][tid + 512] = __uint_as_float((unsigned)v2);
            sm.h[par][tid + 768] = __uint_as_float((unsigned)v3);
        }

        // ---- gather x_t ----
        if constexpr (L == 0) {
            if (tid < K / 4)
                ((float4*)sm.x[par])[tid] = ((const float4*)(S + (size_t)t * K))[tid];
        } else {
            const u64* xrow = xring_in + (size_t)(t & (RING - 1)) * HDIM;
            const unsigned exp = (unsigned)(t + 1);
            u64 v0, v1, v2, v3;
            for (;;) {
                v0 = agload64(xrow + tid);
                v1 = agload64(xrow + tid + 256);
                v2 = agload64(xrow + tid + 512);
                v3 = agload64(xrow + tid + 768);
                if ((unsigned)(v0 >> 32) == exp && (unsigned)(v1 >> 32) == exp &&
                    (unsigned)(v2 >> 32) == exp && (unsigned)(v3 >> 32) == exp)
                    break;
            }
            sm.x[par][tid]       = __uint_as_float((unsigned)v0);
            sm.x[par][tid + 256] = __uint_as_float((unsigned)v1);
            sm.x[par][tid + 512] = __uint_as_float((unsigned)v2);
            sm.x[par][tid + 768] = __uint_as_float((unsigned)v3);
        }

        __syncthreads();   // the ONE barrier per step

        // consumer-progress publish: all threads of WG0 are past the x reads
        if constexpr (L > 0) {
            if (r == 0 && tid == 0) agstorei(progSelf, t + 1);
        }

        // ---- dot products: unit j, k-slice q ----
        float aF = 0.f, aNh = 0.f, aNi = 0.f;
#pragma unroll
        for (int m = 0; m < 16; ++m) {
            const float4 h4 = *(const float4*)&sm.h[par][4 * (q + 16 * m)];
            const float4 wf = *(const float4*)&sm.whh[0][u][4 * (q + 16 * m)];
            const float4 wn = *(const float4*)&sm.whh[1][u][4 * (q + 16 * m)];
            aF  += dot4(wf, h4);
            aNh += dot4(wn, h4);
        }
#pragma unroll
        for (int m = 0; m < K / 64; ++m) {
            const float4 x4 = *(const float4*)&sm.x[par][4 * (q + 16 * m)];
            aF  += dot4(wif[m], x4);
            aNi += dot4(win[m], x4);
        }
#pragma unroll
        for (int off = 8; off; off >>= 1) {
            aF  += __shfl_xor(aF, off, 64);
            aNh += __shfl_xor(aNh, off, 64);
            aNi += __shfl_xor(aNi, off, 64);
        }

        // ---- gate + publish (data carries its own tag; no fence, no flag) --
        if (q == 0) {
            const float f  = 1.f / (1.f + expf(-(aF + bF)));
            const float n  = tanhf(aNi + bIn + f * (aNh + bHn));
            const float hp = sm.h[par][j];
            const float hy = n + (1.f - f) * (hp - n);
            const u64 pk = pack(hy, t + 1);
            agstore64(htag + (size_t)par * HDIM + j, pk);
            if constexpr (L < 2) {
                agstore64(xring_out + (size_t)(t & (RING - 1)) * HDIM + j, pk);
            } else {
                xout[(size_t)t * HDIM + j] = hy;
            }
        }
        // no trailing barrier: s_h/s_x double-buffered by parity; intra-WG
        // skew is bounded to 1 step by the per-step barrier.
    }
}

__global__ __launch_bounds__(256, 1)
void mgu_pipe(const float* __restrict__ S,
              const float* __restrict__ h0,
              const float* __restrict__ w_ih0, const float* __restrict__ b_ih0,
              const float* __restrict__ w_hh0, const float* __restrict__ b_hh0,
              const float* __restrict__ w_ih_r, const float* __restrict__ b_ih_r,
              const float* __restrict__ w_hh_r, const float* __restrict__ b_hh_r,
              float* __restrict__ xbuf2, u64* __restrict__ ring0,
              u64* __restrict__ ring1, u64* __restrict__ htag,
              int* __restrict__ prog)
{
    __shared__ SmemT sm;
    const int grp = blockIdx.x >> 6;
    const int r   = blockIdx.x & 63;
    if (grp == 0) {
        scan_layer<128, 0>(sm, S, nullptr, ring0, nullptr, h0,
                           w_ih0, b_ih0, w_hh0, b_hh0,
                           htag, prog + 1, nullptr, r);
    } else if (grp == 1) {
        scan_layer<1024, 1>(sm, nullptr, ring0, ring1, nullptr, h0 + HDIM,
                            w_ih_r, b_ih_r, w_hh_r, b_hh_r,
                            htag + 2 * HDIM, prog + 2, prog + 1, r);
    } else {
        scan_layer<1024, 2>(sm, nullptr, ring1, nullptr, xbuf2, h0 + 2 * HDIM,
                            w_ih_r + 2048 * 1024, b_ih_r + 2048,
                            w_hh_r + 2048 * 1024, b_hh_r + 2048,
                            htag + 4 * HDIM, nullptr, prog + 2, r);
    }
}

__global__ __launch_bounds__(256)
void mgu_out(const float* __restrict__ x,       // [T, H]
             const float* __restrict__ w_out,   // [1, H]
             const float* __restrict__ b_out,   // [1]
             float* __restrict__ out)           // [T]
{
    const int wave = threadIdx.x >> 6;
    const int lane = threadIdx.x & 63;
    const int t = blockIdx.x * 4 + wave;
    float acc = 0.f;
#pragma unroll
    for (int m = 0; m < 4; ++m) {
        const int i4 = lane + 64 * m;
        const float4 x4 = ((const float4*)(x + (size_t)t * HDIM))[i4];
        const float4 w4 = ((const float4*)w_out)[i4];
        acc += dot4(x4, w4);
    }
#pragma unroll
    for (int off = 32; off > 0; off >>= 1) acc += __shfl_xor(acc, off, 64);
    if (lane == 0) out[t] = acc + b_out[0];
}

extern "C" void kernel_launch(void* const* d_in, const int* in_sizes, int n_in,
                              void* d_out, int out_size, void* d_ws, size_t ws_size,
                              hipStream_t stream) {
    const float* S      = (const float*)d_in[0];   // [8192,128]
    const float* h0     = (const float*)d_in[1];   // [3,1024]
    const float* w_ih0  = (const float*)d_in[2];   // [2048,128]
    const float* w_hh0  = (const float*)d_in[3];   // [2048,1024]
    const float* b_ih0  = (const float*)d_in[4];   // [2048]
    const float* b_hh0  = (const float*)d_in[5];   // [2048]
    const float* w_ih_r = (const float*)d_in[6];   // [2,2048,1024]
    const float* w_hh_r = (const float*)d_in[7];   // [2,2048,1024]
    const float* b_ih_r = (const float*)d_in[8];   // [2,2048]
    const float* b_hh_r = (const float*)d_in[9];   // [2,2048]
    const float* w_out  = (const float*)d_in[10];  // [1,1024]
    const float* b_out  = (const float*)d_in[11];  // [1]
    float* out = (float*)d_out;                    // [8192]

    char* ws = (char*)d_ws;
    float* xbuf2 = (float*)(ws);                        // 32 MB  [T,H] f32
    u64*   ring0 = (u64*)(ws + (32u << 20));            // 1 MB   [RING,H] u64
    u64*   ring1 = (u64*)(ws + (33u << 20));            // 1 MB
    u64*   htag  = (u64*)(ws + (34u << 20));            // 3 x [2,H] u64 = 48 KB
    int*   prog  = (int*)(ws + (34u << 20) + (64u << 10)); // few ints

    // No init kernel: tags/progress use exact-match vs the 0xAA poison.
    mgu_pipe<<<192, 256, 0, stream>>>(S, h0, w_ih0, b_ih0, w_hh0, b_hh0,
                                      w_ih_r, b_ih_r, w_hh_r, b_hh_r,
                                      xbuf2, ring0, ring1, htag, prog);
    mgu_out<<<2048, 256, 0, stream>>>(xbuf2, w_out, b_out, out);
}

// Round 4
// 39181.641 us; speedup vs baseline: 14.7274x; 1.1456x over previous
//
#include <hip/hip_runtime.h>
#include <math.h>
#include <stdint.h>

// MGU RNN, T=8192, IN=128, H=1024, L=3 — pipelined persistent kernel, R4.
// 192 WGs = 3 layer-groups x 64 WGs; WG r of a group owns units [16r,16r+16).
// R4 changes vs R3 (which measured 6.2e9 LDS bank-conflict cycles = 1.6us/step):
//  - ALL weights in VGPRs (256/thread), pinned with an asm "+v" opacity
//    barrier so the compiler cannot remat/reload them in the loop.
//  - LDS holds only h/x (32 KB), read lane-contiguous b128 (conflict-free).
//    Work split: wave a owns units 4a..4a+3; lane q owns elems 4q+256m.
//  - 64-lane butterfly reduction over 12 accumulators; lanes 0..3 compute
//    gates for the wave's 4 units.
// Sync unchanged from R3: tagged 64-bit (tag|float) words through MALL via
// relaxed agent-scope atomics; exact-match tags (0xAA poison never matches);
// one __syncthreads per step; 128-row x rings with amortized backpressure.

#define T_STEPS 8192
#define HDIM 1024
#define RING 128
#define UNITS 16

typedef unsigned long long u64;

__device__ __forceinline__ u64 agload64(const u64* p) {
    return __hip_atomic_load(p, __ATOMIC_RELAXED, __HIP_MEMORY_SCOPE_AGENT);
}
__device__ __forceinline__ void agstore64(u64* p, u64 v) {
    __hip_atomic_store(p, v, __ATOMIC_RELAXED, __HIP_MEMORY_SCOPE_AGENT);
}
__device__ __forceinline__ int agloadi(const int* p) {
    return __hip_atomic_load(p, __ATOMIC_RELAXED, __HIP_MEMORY_SCOPE_AGENT);
}
__device__ __forceinline__ void agstorei(int* p, int v) {
    __hip_atomic_store(p, v, __ATOMIC_RELAXED, __HIP_MEMORY_SCOPE_AGENT);
}
__device__ __forceinline__ float dot4(float4 a, float4 b) {
    return a.x * b.x + a.y * b.y + a.z * b.z + a.w * b.w;
}
__device__ __forceinline__ u64 pack(float v, int tag) {
    return ((u64)(unsigned)tag << 32) | (u64)__float_as_uint(v);
}
// Opacity barrier: value becomes non-rematerializable -> stays in VGPRs.
__device__ __forceinline__ void opaque4(float4& v) {
    asm volatile("" : "+v"(v.x), "+v"(v.y), "+v"(v.z), "+v"(v.w));
}
__device__ __forceinline__ void opaque2(float2& v) {
    asm volatile("" : "+v"(v.x), "+v"(v.y));
}

// K: input width. L: layer index 0..2.
template <int K, int L>
__device__ void scan_layer(float* __restrict__ s_h,  // [2][HDIM] LDS
                           float* __restrict__ s_x,  // [2][HDIM] LDS
                           const float* __restrict__ S,        // L==0: [T,K]
                           const u64*  __restrict__ xring_in,  // L>0
                           u64*        __restrict__ xring_out, // L<2
                           float*      __restrict__ xout,      // L==2: [T,H]
                           const float* __restrict__ h0,       // [H]
                           const float* __restrict__ w_ih,
                           const float* __restrict__ b_ih,
                           const float* __restrict__ w_hh,
                           const float* __restrict__ b_hh,
                           u64* __restrict__ htag,             // [2,H] tagged
                           int* __restrict__ progNext,         // L<2
                           int* __restrict__ progSelf,         // L>0
                           int r)
{
    const int tid = threadIdx.x;
    const int a   = tid >> 6;          // wave 0..3 -> units 4a..4a+3
    const int q   = tid & 63;          // lane -> elems 4q+256m, m=0..3
    const int jb  = r * UNITS + 4 * a; // base unit row for this wave

    // ---- weights -> VGPRs (once), pinned opaque ----
    float4 wf[4][4], wn[4][4];         // [g][m] W_hh rows jb+g / H+jb+g
#pragma unroll
    for (int g = 0; g < 4; ++g) {
        const float* rf = w_hh + (size_t)(jb + g) * HDIM;
        const float* rn = w_hh + (size_t)(HDIM + jb + g) * HDIM;
#pragma unroll
        for (int m = 0; m < 4; ++m) {
            wf[g][m] = *(const float4*)(rf + 4 * q + 256 * m);
            wn[g][m] = *(const float4*)(rn + 4 * q + 256 * m);
            opaque4(wf[g][m]); opaque4(wn[g][m]);
        }
    }
    float4 wif[4][4], win[4][4];       // K==1024 input weights
    float2 wif2[4], win2[4];           // K==128 input weights
    if constexpr (K == 1024) {
#pragma unroll
        for (int g = 0; g < 4; ++g) {
            const float* rf = w_ih + (size_t)(jb + g) * K;
            const float* rn = w_ih + (size_t)(HDIM + jb + g) * K;
#pragma unroll
            for (int m = 0; m < 4; ++m) {
                wif[g][m] = *(const float4*)(rf + 4 * q + 256 * m);
                win[g][m] = *(const float4*)(rn + 4 * q + 256 * m);
                opaque4(wif[g][m]); opaque4(win[g][m]);
            }
        }
    } else {
#pragma unroll
        for (int g = 0; g < 4; ++g) {
            wif2[g] = *(const float2*)(w_ih + (size_t)(jb + g) * K + 2 * q);
            win2[g] = *(const float2*)(w_ih + (size_t)(HDIM + jb + g) * K + 2 * q);
            opaque2(wif2[g]); opaque2(win2[g]);
        }
    }
    float bF[4], bIn[4], bHn[4];       // wave-uniform
#pragma unroll
    for (int g = 0; g < 4; ++g) {
        bF[g]  = b_ih[jb + g] + b_hh[jb + g];
        bIn[g] = b_ih[HDIM + jb + g];
        bHn[g] = b_hh[HDIM + jb + g];
    }

    int lastProg = 0;
    for (int t = 0; t < T_STEPS; ++t) {
        const int par = t & 1;
        float* hD = s_h + par * HDIM;
        float* xD = s_x + par * HDIM;

        if constexpr (L < 2) {
            if (t - lastProg > RING - 8) {
                do { lastProg = agloadi(progNext); } while (t - lastProg > RING - 8);
            }
        }

        // ---- gather h_{t-1} (+ x_t for L>0): merged tagged poll ----
        if (t == 0) {
            ((float4*)hD)[tid] = ((const float4*)h0)[tid];
        }
        {
            const u64* hrow = htag + (size_t)((t - 1) & 1) * HDIM;
            const unsigned he = (unsigned)t;
            const u64* xrow = (L > 0) ? xring_in + (size_t)(t & (RING - 1)) * HDIM
                                      : nullptr;
            const unsigned xe = (unsigned)(t + 1);
            u64 h0v=0,h1v=0,h2v=0,h3v=0, x0v=0,x1v=0,x2v=0,x3v=0;
            bool hd = (t == 0);
            bool d0=hd,d1=hd,d2=hd,d3=hd;
            bool e0=(L==0),e1=(L==0),e2=(L==0),e3=(L==0);
            while (!(d0&&d1&&d2&&d3&&e0&&e1&&e2&&e3)) {
                if (!d0) { h0v=agload64(hrow+tid);     d0=((unsigned)(h0v>>32)==he); }
                if (!d1) { h1v=agload64(hrow+tid+256); d1=((unsigned)(h1v>>32)==he); }
                if (!d2) { h2v=agload64(hrow+tid+512); d2=((unsigned)(h2v>>32)==he); }
                if (!d3) { h3v=agload64(hrow+tid+768); d3=((unsigned)(h3v>>32)==he); }
                if constexpr (L > 0) {
                    if (!e0) { x0v=agload64(xrow+tid);     e0=((unsigned)(x0v>>32)==xe); }
                    if (!e1) { x1v=agload64(xrow+tid+256); e1=((unsigned)(x1v>>32)==xe); }
                    if (!e2) { x2v=agload64(xrow+tid+512); e2=((unsigned)(x2v>>32)==xe); }
                    if (!e3) { x3v=agload64(xrow+tid+768); e3=((unsigned)(x3v>>32)==xe); }
                }
            }
            if (t > 0) {
                hD[tid]       = __uint_as_float((unsigned)h0v);
                hD[tid + 256] = __uint_as_float((unsigned)h1v);
                hD[tid + 512] = __uint_as_float((unsigned)h2v);
                hD[tid + 768] = __uint_as_float((unsigned)h3v);
            }
            if constexpr (L > 0) {
                xD[tid]       = __uint_as_float((unsigned)x0v);
                xD[tid + 256] = __uint_as_float((unsigned)x1v);
                xD[tid + 512] = __uint_as_float((unsigned)x2v);
                xD[tid + 768] = __uint_as_float((unsigned)x3v);
            }
        }
        if constexpr (L == 0) {
            if (tid < K / 4)
                ((float4*)xD)[tid] = ((const float4*)(S + (size_t)t * K))[tid];
        }
        __syncthreads();   // the ONE barrier per step

        if constexpr (L > 0) {
            if (r == 0 && tid == 0) agstorei(progSelf, t + 1);
        }

        // ---- dots: lane-contiguous b128 LDS reads (conflict-free) ----
        float aF[4]  = {0.f, 0.f, 0.f, 0.f};
        float aNh[4] = {0.f, 0.f, 0.f, 0.f};
        float aNi[4] = {0.f, 0.f, 0.f, 0.f};
#pragma unroll
        for (int m = 0; m < 4; ++m) {
            const float4 h4 = ((const float4*)hD)[q + 64 * m];
#pragma unroll
            for (int g = 0; g < 4; ++g) {
                aF[g]  += dot4(wf[g][m], h4);
                aNh[g] += dot4(wn[g][m], h4);
            }
        }
        if constexpr (K == 1024) {
#pragma unroll
            for (int m = 0; m < 4; ++m) {
                const float4 x4 = ((const float4*)xD)[q + 64 * m];
#pragma unroll
                for (int g = 0; g < 4; ++g) {
                    aF[g]  += dot4(wif[g][m], x4);
                    aNi[g] += dot4(win[g][m], x4);
                }
            }
        } else {
            const float2 x2 = ((const float2*)xD)[q];
#pragma unroll
            for (int g = 0; g < 4; ++g) {
                aF[g]  += wif2[g].x * x2.x + wif2[g].y * x2.y;
                aNi[g] += win2[g].x * x2.x + win2[g].y * x2.y;
            }
        }
        // ---- 64-lane butterfly over 12 accumulators ----
#pragma unroll
        for (int off = 32; off; off >>= 1) {
#pragma unroll
            for (int g = 0; g < 4; ++g) {
                aF[g]  += __shfl_xor(aF[g],  off, 64);
                aNh[g] += __shfl_xor(aNh[g], off, 64);
                aNi[g] += __shfl_xor(aNi[g], off, 64);
            }
        }

        // ---- gates + publish: lane g (0..3) handles unit jb+g ----
        if (q < 4) {
            const float vF  = (q==0)?aF[0] :(q==1)?aF[1] :(q==2)?aF[2] :aF[3];
            const float vNh = (q==0)?aNh[0]:(q==1)?aNh[1]:(q==2)?aNh[2]:aNh[3];
            const float vNi = (q==0)?aNi[0]:(q==1)?aNi[1]:(q==2)?aNi[2]:aNi[3];
            const float cF  = (q==0)?bF[0] :(q==1)?bF[1] :(q==2)?bF[2] :bF[3];
            const float cIn = (q==0)?bIn[0]:(q==1)?bIn[1]:(q==2)?bIn[2]:bIn[3];
            const float cHn = (q==0)?bHn[0]:(q==1)?bHn[1]:(q==2)?bHn[2]:bHn[3];
            const int j = jb + q;
            const float f  = 1.f / (1.f + expf(-(vF + cF)));
            const float n  = tanhf(vNi + cIn + f * (vNh + cHn));
            const float hp = hD[j];
            const float hy = n + (1.f - f) * (hp - n);
            const u64 pk = pack(hy, t + 1);
            agstore64(htag + (size_t)par * HDIM + j, pk);
            if constexpr (L < 2) {
                agstore64(xring_out + (size_t)(t & (RING - 1)) * HDIM + j, pk);
            } else {
                xout[(size_t)t * HDIM + j] = hy;
            }
        }
        // no trailing barrier: parity double-buffering + per-step barrier
        // bounds intra-WG skew to 1 step (see R3 analysis).
    }
}

__global__ __launch_bounds__(256, 1)
void mgu_pipe(const float* __restrict__ S,
              const float* __restrict__ h0,
              const float* __restrict__ w_ih0, const float* __restrict__ b_ih0,
              const float* __restrict__ w_hh0, const float* __restrict__ b_hh0,
              const float* __restrict__ w_ih_r, const float* __restrict__ b_ih_r,
              const float* __restrict__ w_hh_r, const float* __restrict__ b_hh_r,
              float* __restrict__ xbuf2, u64* __restrict__ ring0,
              u64* __restrict__ ring1, u64* __restrict__ htag,
              int* __restrict__ prog)
{
    __shared__ __align__(16) float s_h[2 * HDIM];
    __shared__ __align__(16) float s_x[2 * HDIM];
    const int grp = blockIdx.x >> 6;
    const int r   = blockIdx.x & 63;
    if (grp == 0) {
        scan_layer<128, 0>(s_h, s_x, S, nullptr, ring0, nullptr, h0,
                           w_ih0, b_ih0, w_hh0, b_hh0,
                           htag, prog + 1, nullptr, r);
    } else if (grp == 1) {
        scan_layer<1024, 1>(s_h, s_x, nullptr, ring0, ring1, nullptr, h0 + HDIM,
                            w_ih_r, b_ih_r, w_hh_r, b_hh_r,
                            htag + 2 * HDIM, prog + 2, prog + 1, r);
    } else {
        scan_layer<1024, 2>(s_h, s_x, nullptr, ring1, nullptr, xbuf2,
                            h0 + 2 * HDIM,
                            w_ih_r + 2048 * 1024, b_ih_r + 2048,
                            w_hh_r + 2048 * 1024, b_hh_r + 2048,
                            htag + 4 * HDIM, nullptr, prog + 2, r);
    }
}

__global__ __launch_bounds__(256)
void mgu_out(const float* __restrict__ x,       // [T, H]
             const float* __restrict__ w_out,   // [1, H]
             const float* __restrict__ b_out,   // [1]
             float* __restrict__ out)           // [T]
{
    const int wave = threadIdx.x >> 6;
    const int lane = threadIdx.x & 63;
    const int t = blockIdx.x * 4 + wave;
    float acc = 0.f;
#pragma unroll
    for (int m = 0; m < 4; ++m) {
        const int i4 = lane + 64 * m;
        const float4 x4 = ((const float4*)(x + (size_t)t * HDIM))[i4];
        const float4 w4 = ((const float4*)w_out)[i4];
        acc += dot4(x4, w4);
    }
#pragma unroll
    for (int off = 32; off > 0; off >>= 1) acc += __shfl_xor(acc, off, 64);
    if (lane == 0) out[t] = acc + b_out[0];
}

extern "C" void kernel_launch(void* const* d_in, const int* in_sizes, int n_in,
                              void* d_out, int out_size, void* d_ws, size_t ws_size,
                              hipStream_t stream) {
    const float* S      = (const float*)d_in[0];   // [8192,128]
    const float* h0     = (const float*)d_in[1];   // [3,1024]
    const float* w_ih0  = (const float*)d_in[2];   // [2048,128]
    const float* w_hh0  = (const float*)d_in[3];   // [2048,1024]
    const float* b_ih0  = (const float*)d_in[4];   // [2048]
    const float* b_hh0  = (const float*)d_in[5];   // [2048]
    const float* w_ih_r = (const float*)d_in[6];   // [2,2048,1024]
    const float* w_hh_r = (const float*)d_in[7];   // [2,2048,1024]
    const float* b_ih_r = (const float*)d_in[8];   // [2,2048]
    const float* b_hh_r = (const float*)d_in[9];   // [2,2048]
    const float* w_out  = (const float*)d_in[10];  // [1,1024]
    const float* b_out  = (const float*)d_in[11];  // [1]
    float* out = (float*)d_out;                    // [8192]

    char* ws = (char*)d_ws;
    float* xbuf2 = (float*)(ws);                        // 32 MB  [T,H] f32
    u64*   ring0 = (u64*)(ws + (32u << 20));            // 1 MB   [RING,H] u64
    u64*   ring1 = (u64*)(ws + (33u << 20));            // 1 MB
    u64*   htag  = (u64*)(ws + (34u << 20));            // 3 x [2,H] u64 = 48 KB
    int*   prog  = (int*)(ws + (34u << 20) + (64u << 10)); // few ints

    // No init kernel: tags/progress use exact-match vs the 0xAA poison.
    mgu_pipe<<<192, 256, 0, stream>>>(S, h0, w_ih0, b_ih0, w_hh0, b_hh0,
                                      w_ih_r, b_ih_r, w_hh_r, b_hh_r,
                                      xbuf2, ring0, ring1, htag, prog);
    mgu_out<<<2048, 256, 0, stream>>>(xbuf2, w_out, b_out, out);
}